// Round 10
// baseline (202.321 us; speedup 1.0000x reference)
//
#include <hip/hip_runtime.h>
#include <math.h>

// ---------------------------------------------------------------------------
// SpectralGroupAttention: [prep: weight bf16-pairs (incl. fnn1_w) + A-check]
// -> [MEGA2 (1024 thr): conv1d+leaky+RMSNorm (wave-per-row, barrier-free) ->
//  GEMM(inp|D) -> seqconv -> GEMM(convlin) -> GEMM(fc1|2|3,softplus) ->
//  [M=C.B^T (waves 4-12)  ||  scan u/eS cumsum (threads 0-255)] ->
//  triangle+gate -> GEMM(out_w) -> F bf16 pairs] ->
// [fnn1 MFMA split-K (4x17 blocks) -> partials] -> fnn2.
// Sequential fallback kept for general A (scan_fb + tail_cold, early-exit).
// All GEMMs (incl. fnn1) use split-bf16 (hi+lo, 3 MFMA products).
// B=256, L=34, d=128, di=256, N=128, M=8704.
// ---------------------------------------------------------------------------

#define NB    256
#define LL    34
#define DD    128
#define DI    256
#define NN    128
#define MM    (NB*LL)       // 8704

using u16 = unsigned short;
typedef __attribute__((ext_vector_type(8))) short short8;
typedef __attribute__((ext_vector_type(4))) float f32x4;

__device__ __forceinline__ float silu_f(float x)  { return x / (1.f + __expf(-x)); }
__device__ __forceinline__ float softplus_f(float x) {
    return fmaxf(x, 0.f) + __logf(1.f + __expf(-fabsf(x)));
}
__device__ __forceinline__ float leaky_f(float x) { return (x >= 0.f) ? x : 0.01f * x; }

__device__ __forceinline__ u16 f2bf(float x) {            // RNE fp32->bf16
    unsigned u = __float_as_uint(x);
    return (u16)((u + 0x7FFF + ((u >> 16) & 1)) >> 16);
}
__device__ __forceinline__ float bf2f(u16 h) {
    return __uint_as_float(((unsigned)h) << 16);
}
__device__ __forceinline__ void f2pair(float v, u16* h, u16* l) {
    u16 hh = f2bf(v);
    *h = hh;
    *l = f2bf(v - bf2f(hh));
}

// ---------------------------------------------------------------------------
// prep_k: weight bf16-pair conversion + bias concat (blocks [0,2240));
// A-uniformity check (block 2240).  fnn1_w converted in natural [64][4352]
// layout (MFMA B-operand) -- no transpose needed.
// ---------------------------------------------------------------------------
__global__ __launch_bounds__(256)
void prep_k(const float* __restrict__ inp_w, const float* __restrict__ D_w,
            const float* __restrict__ fc1_w, const float* __restrict__ fc2_w,
            const float* __restrict__ fc3_w, const float* __restrict__ convlin_w,
            const float* __restrict__ out_w,
            const float* __restrict__ inp_b, const float* __restrict__ D_b,
            const float* __restrict__ fc1_b, const float* __restrict__ fc2_b,
            const float* __restrict__ fc3_b,
            const float* __restrict__ W1, const float* __restrict__ A,
            u16* __restrict__ wc1h, u16* __restrict__ wc1l,
            u16* __restrict__ wc3h, u16* __restrict__ wc3l,
            u16* __restrict__ cvh,  u16* __restrict__ cvl,
            u16* __restrict__ owh,  u16* __restrict__ owl,
            u16* __restrict__ w1h,  u16* __restrict__ w1l,
            float* __restrict__ bias1, float* __restrict__ bias3,
            int* __restrict__ flag)
{
    const int bx  = blockIdx.x;
    const int tid = threadIdx.x;

    if (bx < 2240) {
        int i = bx * 256 + tid;
        if (i < 65536) {
            float v = (i < 32768) ? inp_w[i] : D_w[i - 32768];
            f2pair(v, &wc1h[i], &wc1l[i]);
        } else if (i < 196608) {
            int j = i - 65536;
            float v = (j < 65536) ? fc1_w[j] : (j < 98304 ? fc2_w[j - 65536] : fc3_w[j - 98304]);
            f2pair(v, &wc3h[j], &wc3l[j]);
        } else if (i < 262144) {
            int j = i - 196608;
            f2pair(convlin_w[j], &cvh[j], &cvl[j]);
        } else if (i < 294912) {
            int j = i - 262144;
            f2pair(out_w[j], &owh[j], &owl[j]);
        } else if (i < 573440) {
            int j = i - 294912;
            f2pair(W1[j], &w1h[j], &w1l[j]);
        }
        if (i < 512)  bias1[i] = (i < 256) ? inp_b[i] : D_b[i - 256];
        else if (i < 1024) {
            int j = i - 512;
            bias3[j] = (j < 256) ? fc1_b[j] : (j < 384 ? fc2_b[j - 256] : fc3_b[j - 384]);
        }
    } else {
        __shared__ int s;
        if (tid == 0) s = 1;
        __syncthreads();
        bool ok = true;
        for (int k = 0; k < 128; k++) {
            int idx = tid + k * 256;
            ok &= (A[idx] == A[idx & ~127]);
        }
        if (!ok) s = 0;
        __syncthreads();
        if (tid == 0) *flag = s;
    }
}

// ---------------------------------------------------------------------------
// MEGA2: per-batch fused pipeline.  256 blocks x 1024 threads, ~142 KB LDS,
// 1 block/CU.  (Round-9 winner; G4 epilogue now emits F bf16 pairs.)
// ---------------------------------------------------------------------------
__global__ __launch_bounds__(1024, 1)
void mega2_k(const int* __restrict__ flag,
             const float* __restrict__ x,
             const float* __restrict__ cw, const float* __restrict__ cb,
             const float* __restrict__ nw,
             const u16* __restrict__ wc1h, const u16* __restrict__ wc1l,
             const float* __restrict__ bias1,
             const float* __restrict__ scw, const float* __restrict__ scb,
             const u16* __restrict__ cvh, const u16* __restrict__ cvl,
             const float* __restrict__ clb,
             const u16* __restrict__ wc3h, const u16* __restrict__ wc3l,
             const float* __restrict__ bias3,
             const float* __restrict__ A,
             const u16* __restrict__ owh, const u16* __restrict__ owl,
             const float* __restrict__ outb,
             float* __restrict__ buf1,           // cold: dgate spill cols 256+
             float* __restrict__ buf3,           // delta (always); B|C cold
             u16* __restrict__ bcpair,           // cold only
             u16* __restrict__ xc2h, u16* __restrict__ xc2l, // cold only
             u16* __restrict__ Fh, u16* __restrict__ Fl)     // F pairs out
{
    const int b    = blockIdx.x;
    const int tid  = threadIdx.x;
    const int wave = tid >> 6;
    const int lane = tid & 63;
    const int l15  = lane & 15;
    const int lq   = lane >> 4;

    // ---- LDS overlay plan (144944 B) ----
    __shared__ __align__(16) char smem[144944];
    float (*sx)[264] = (float (*)[264])(smem);
    float (*sw)[112] = (float (*)[112])(smem + 35904);
    u16 (*sXch)[264] = (u16 (*)[264])(smem);
    u16 (*sXcl)[264] = (u16 (*)[264])(smem + 25344);
    u16 (*sBh)[136]  = (u16 (*)[136])(smem);
    u16 (*sBl)[136]  = (u16 (*)[136])(smem + 13056);
    u16 (*sCh)[136]  = (u16 (*)[136])(smem + 26112);
    u16 (*sCl)[136]  = (u16 (*)[136])(smem + 39168);
    u16 (*sGh)[264]  = (u16 (*)[264])(smem);
    u16 (*sGl)[264]  = (u16 (*)[264])(smem + 25344);
    u16 (*sXnh)[136] = (u16 (*)[136])(smem + 52224);   // dead before sX2 writes
    u16 (*sXnl)[136] = (u16 (*)[136])(smem + 65280);
    u16 (*sX2h)[264] = (u16 (*)[264])(smem + 52224);
    u16 (*sX2l)[264] = (u16 (*)[264])(smem + 77568);
    float (*sM)[49]  = (float (*)[49])(smem + 102912);
    float (*sDG)[260]= (float (*)[260])(smem + 109584);

    const bool uni = (*flag != 0);

    // ---- stage seqconv weights + sx pad (independent of conv) ----
    for (int idx = tid; idx < LL * LL * 3; idx += 1024) {
        int lo = idx / 102;
        int rem = idx - lo * 102;
        int li = rem / 3;
        int k  = rem - li * 3;
        sw[li][lo * 3 + k] = scw[idx];
    }
    if (tid < LL) { sx[tid][0] = 0.f; sx[tid][257] = 0.f; }

    // ---- phase 0: conv1d+leaky+RMSNorm, one row per wave, 0 barriers ----
    {
        const int t = lane;
        #pragma unroll
        for (int pass = 0; pass < 3; pass++) {
            const int rr = pass * 16 + wave;
            if (rr < LL) {
                const float* xr = x + (size_t)b * 189 + rr * 5;
                float xv[20];
                #pragma unroll
                for (int k = 0; k < 20; k++) xv[k] = xr[k];
                float g0 = cb[t];
                float g1 = cb[t + 64];
                #pragma unroll
                for (int k = 0; k < 20; k++) {
                    g0 = fmaf(xv[k], cw[t * 20 + k], g0);
                    g1 = fmaf(xv[k], cw[(t + 64) * 20 + k], g1);
                }
                g0 = leaky_f(g0);
                g1 = leaky_f(g1);
                float s = fmaf(g1, g1, g0 * g0);
                #pragma unroll
                for (int m = 32; m >= 1; m >>= 1) s += __shfl_xor(s, m);
                float inv = 1.f / sqrtf(s * (1.f / 128.f) + 1e-5f);
                float v0 = g0 * inv * nw[t];
                float v1 = g1 * inv * nw[t + 64];
                f2pair(v0, &sXnh[rr][t], &sXnl[rr][t]);
                f2pair(v1, &sXnh[rr][t + 64], &sXnl[rr][t + 64]);
            }
        }
    }
    __syncthreads();

    // ---- G1: xp|dgate = xn @ [inp_w;D_w].T + bias1 (K=128, barrier-free) ----
    {
        const int c0 = wave * 32;
        f32x4 a1[3][2];
        #pragma unroll
        for (int i = 0; i < 3; i++)
            #pragma unroll
            for (int j = 0; j < 2; j++) a1[i][j] = (f32x4){0.f, 0.f, 0.f, 0.f};

        #pragma unroll
        for (int ks = 0; ks < 4; ks++) {
            short8 fh[3], fl[3];
            #pragma unroll
            for (int i = 0; i < 3; i++) {
                fh[i] = *(const short8*)&sXnh[i * 16 + l15][ks * 32 + lq * 8];
                fl[i] = *(const short8*)&sXnl[i * 16 + l15][ks * 32 + lq * 8];
            }
            #pragma unroll
            for (int j = 0; j < 2; j++) {
                const size_t wo = (size_t)(c0 + j * 16 + l15) * 128 + ks * 32 + lq * 8;
                short8 bh = *(const short8*)&wc1h[wo];
                short8 bl = *(const short8*)&wc1l[wo];
                #pragma unroll
                for (int i = 0; i < 3; i++) {
                    a1[i][j] = __builtin_amdgcn_mfma_f32_16x16x32_bf16(fh[i], bh, a1[i][j], 0, 0, 0);
                    a1[i][j] = __builtin_amdgcn_mfma_f32_16x16x32_bf16(fh[i], bl, a1[i][j], 0, 0, 0);
                    a1[i][j] = __builtin_amdgcn_mfma_f32_16x16x32_bf16(fl[i], bh, a1[i][j], 0, 0, 0);
                }
            }
        }
        #pragma unroll
        for (int i = 0; i < 3; i++) {
            int row = i * 16 + lq * 4;
            #pragma unroll
            for (int j = 0; j < 2; j++) {
                int col = c0 + j * 16 + l15;
                float bb = bias1[col];
                #pragma unroll
                for (int r = 0; r < 4; r++) {
                    float v = a1[i][j][r] + bb;
                    int rr = row + r;
                    if (rr < LL) {
                        if (col < 256) {
                            sx[rr][col + 1] = v;          // xp -> seqconv input
                        } else {
                            sDG[rr][col - 256] = v;       // dgate fp32 (hot)
                            if (!uni)
                                buf1[((size_t)b * LL + rr) * 512 + col] = v;
                        }
                    }
                }
            }
        }
    }
    __syncthreads();

    // ---- seqconv compute (rows split over 16 groups) ----
    {
        const int tx  = tid & 63;
        const int ty  = tid >> 6;            // 0..15
        const int j0c = tx * 4;
        const int cbase = (ty < 2) ? ty * 3 : 6 + (ty - 2) * 2;
        const int ccnt  = (ty < 2) ? 3 : 2;

        float cacc[3][4];
        #pragma unroll
        for (int i = 0; i < 3; i++)
            #pragma unroll
            for (int jj = 0; jj < 4; jj++) cacc[i][jj] = 0.f;

        for (int li = 0; li < LL; li++) {
            float4 xa = *(const float4*)&sx[li][j0c];
            float2 xb = *(const float2*)&sx[li][j0c + 4];
            float xv[6] = {xa.x, xa.y, xa.z, xa.w, xb.x, xb.y};
            const float* swr = &sw[li][0];
            #pragma unroll
            for (int i = 0; i < 3; i++) {
                if (i < ccnt) {
                    int lo3 = (cbase + i) * 3;
                    float w0 = swr[lo3 + 0];
                    float w1 = swr[lo3 + 1];
                    float w2 = swr[lo3 + 2];
                    #pragma unroll
                    for (int jj = 0; jj < 4; jj++) {
                        cacc[i][jj] = fmaf(w0, xv[jj],     cacc[i][jj]);
                        cacc[i][jj] = fmaf(w1, xv[jj + 1], cacc[i][jj]);
                        cacc[i][jj] = fmaf(w2, xv[jj + 2], cacc[i][jj]);
                    }
                }
            }
        }
        __syncthreads();          // sx/sw reads done; regionA reusable

        #pragma unroll
        for (int i = 0; i < 3; i++) {
            if (i < ccnt) {
                int lo = cbase + i;
                float bb = scb[lo];
                ushort4 oh, ol;
                float v0 = silu_f(cacc[i][0] + bb);
                float v1 = silu_f(cacc[i][1] + bb);
                float v2 = silu_f(cacc[i][2] + bb);
                float v3 = silu_f(cacc[i][3] + bb);
                f2pair(v0, &oh.x, &ol.x);
                f2pair(v1, &oh.y, &ol.y);
                f2pair(v2, &oh.z, &ol.z);
                f2pair(v3, &oh.w, &ol.w);
                *(ushort4*)&sXch[lo][j0c] = oh;
                *(ushort4*)&sXcl[lo][j0c] = ol;
            }
        }
    }
    __syncthreads();

    // ---- G2: xc2 = xc @ convlin.T + bias (barrier-free K-loop) ----
    {
        const int c0 = wave * 16;
        f32x4 a2[3];
        #pragma unroll
        for (int i = 0; i < 3; i++) a2[i] = (f32x4){0.f, 0.f, 0.f, 0.f};

        #pragma unroll
        for (int ks = 0; ks < 8; ks++) {
            short8 fh[3], fl[3];
            #pragma unroll
            for (int i = 0; i < 3; i++) {
                fh[i] = *(const short8*)&sXch[i * 16 + l15][ks * 32 + lq * 8];
                fl[i] = *(const short8*)&sXcl[i * 16 + l15][ks * 32 + lq * 8];
            }
            const size_t wo = (size_t)(c0 + l15) * 256 + ks * 32 + lq * 8;
            short8 bh = *(const short8*)&cvh[wo];
            short8 bl = *(const short8*)&cvl[wo];
            #pragma unroll
            for (int i = 0; i < 3; i++) {
                a2[i] = __builtin_amdgcn_mfma_f32_16x16x32_bf16(fh[i], bh, a2[i], 0, 0, 0);
                a2[i] = __builtin_amdgcn_mfma_f32_16x16x32_bf16(fh[i], bl, a2[i], 0, 0, 0);
                a2[i] = __builtin_amdgcn_mfma_f32_16x16x32_bf16(fl[i], bh, a2[i], 0, 0, 0);
            }
        }
        #pragma unroll
        for (int i = 0; i < 3; i++) {
            int row = i * 16 + lq * 4;
            int col = c0 + l15;
            float bb = clb[col];
            #pragma unroll
            for (int r = 0; r < 4; r++) {
                float v = a2[i][r] + bb;
                u16 hh, ll;
                f2pair(v, &hh, &ll);
                sX2h[row + r][col] = hh;
                sX2l[row + r][col] = ll;
                if (!uni && (row + r) < LL) {
                    xc2h[(size_t)(b * LL + row + r) * 256 + col] = hh;
                    xc2l[(size_t)(b * LL + row + r) * 256 + col] = ll;
                }
            }
        }
    }
    __syncthreads();

    // ---- G3: delta|B|C = xc2 @ [fc1;fc2;fc3].T + bias (barrier-free K) ----
    {
        const int c0 = wave * 32;
        f32x4 a3[3][2];
        #pragma unroll
        for (int i = 0; i < 3; i++)
            #pragma unroll
            for (int j = 0; j < 2; j++) a3[i][j] = (f32x4){0.f, 0.f, 0.f, 0.f};

        #pragma unroll
        for (int ks = 0; ks < 8; ks++) {
            short8 fh[3], fl[3];
            #pragma unroll
            for (int i = 0; i < 3; i++) {
                fh[i] = *(const short8*)&sX2h[i * 16 + l15][ks * 32 + lq * 8];
                fl[i] = *(const short8*)&sX2l[i * 16 + l15][ks * 32 + lq * 8];
            }
            #pragma unroll
            for (int j = 0; j < 2; j++) {
                const size_t wo = (size_t)(c0 + j * 16 + l15) * 256 + ks * 32 + lq * 8;
                short8 bh = *(const short8*)&wc3h[wo];
                short8 bl = *(const short8*)&wc3l[wo];
                #pragma unroll
                for (int i = 0; i < 3; i++) {
                    a3[i][j] = __builtin_amdgcn_mfma_f32_16x16x32_bf16(fh[i], bh, a3[i][j], 0, 0, 0);
                    a3[i][j] = __builtin_amdgcn_mfma_f32_16x16x32_bf16(fh[i], bl, a3[i][j], 0, 0, 0);
                    a3[i][j] = __builtin_amdgcn_mfma_f32_16x16x32_bf16(fl[i], bh, a3[i][j], 0, 0, 0);
                }
            }
        }
        #pragma unroll
        for (int i = 0; i < 3; i++) {
            int row = i * 16 + lq * 4;
            #pragma unroll
            for (int j = 0; j < 2; j++) {
                int col = c0 + j * 16 + l15;
                float bb = bias3[col];
                #pragma unroll
                for (int r = 0; r < 4; r++) {
                    float v = a3[i][j][r] + bb;
                    int rr = row + r;
                    if (col < 256) {
                        v = softplus_f(v);
                        if (rr < LL) buf3[((size_t)b * LL + rr) * 512 + col] = v;
                    } else {
                        u16 hh, ll;
                        f2pair(v, &hh, &ll);
                        int cc = col & 127;
                        if (col < 384) { sBh[rr][cc] = hh; sBl[rr][cc] = ll; }
                        else           { sCh[rr][cc] = hh; sCl[rr][cc] = ll; }
                        if (!uni && rr < LL) {
                            buf3[((size_t)b * LL + rr) * 512 + col] = v;
                            u16* rb = bcpair + ((size_t)b * LL + rr) * 1024
                                      + ((col < 384) ? 0 : 256) + cc;
                            rb[0]   = hh;
                            rb[128] = ll;
                        }
                    }
                }
            }
        }
    }
    __syncthreads();
    if (!uni) return;             // cold path -> scan_fb + tail_cold

    // ---- OVERLAPPED: threads 0-255 scan u/eS cumsum (regs) ||
    //      waves 4-12: M = C.B^T ----
    float u[LL], eS[LL];
    if (tid < 256) {
        const int d = tid;
        const float a_d = A[(size_t)d * NN];
        const float* pDel = buf3 + (size_t)b * LL * 512 + d;    // stride 512
        float S = 0.f;
        #pragma unroll
        for (int l = 0; l < LL; l++) {
            float dl = pDel[l * 512];
            S = fmaf(dl, a_d, S);
            eS[l] = __expf(S);
            float xv = bf2f(sX2h[l][d]) + bf2f(sX2l[l][d]);
            u[l] = __expf(-S) * dl * xv;
        }
    } else if (wave >= 4 && wave < 13) {
        int tt = wave - 4;
        int ti = tt / 3, tj = tt - ti * 3;
        f32x4 acc = (f32x4){0.f, 0.f, 0.f, 0.f};
        #pragma unroll
        for (int ks = 0; ks < 4; ks++) {
            short8 ch = *(const short8*)&sCh[ti * 16 + l15][ks * 32 + lq * 8];
            short8 cl = *(const short8*)&sCl[ti * 16 + l15][ks * 32 + lq * 8];
            short8 bh = *(const short8*)&sBh[tj * 16 + l15][ks * 32 + lq * 8];
            short8 bl = *(const short8*)&sBl[tj * 16 + l15][ks * 32 + lq * 8];
            acc = __builtin_amdgcn_mfma_f32_16x16x32_bf16(ch, bh, acc, 0, 0, 0);
            acc = __builtin_amdgcn_mfma_f32_16x16x32_bf16(ch, bl, acc, 0, 0, 0);
            acc = __builtin_amdgcn_mfma_f32_16x16x32_bf16(cl, bh, acc, 0, 0, 0);
        }
        #pragma unroll
        for (int r = 0; r < 4; r++) {
            int row = ti * 16 + lq * 4 + r;
            if (row < LL) sM[row][tj * 16 + l15] = acc[r];
        }
    }
    __syncthreads();

    // ---- triangle + gate (threads 0-255); waves 4-15 zero gate pad rows ----
    if (tid < 256) {
        const int d = tid;
        #pragma unroll
        for (int l = 0; l < LL; l++) {
            float acc = 0.f;
            for (int t = 0; t <= l; t++) acc = fmaf(sM[l][t], u[t], acc);
            float xs = eS[l] * acc;
            float g = silu_f(xs) * silu_f(sDG[l][d]);
            u16 hh, ll2;
            f2pair(g, &hh, &ll2);
            sGh[l][d] = hh;
            sGl[l][d] = ll2;
        }
    } else {
        u16* zh = &sGh[34][0];
        u16* zl = &sGl[34][0];
        for (int idx = tid - 256; idx < 14 * 264; idx += 768) {
            zh[idx] = 0;
            zl[idx] = 0;
        }
    }
    __syncthreads();

    // ---- F = gate @ out_w.T + out_b -> bf16 pairs (row b, k = l*128+col) ----
    {
        const int j0 = wave & 7;
        const int i0 = (wave >> 3) ? 2 : 0;
        const int ni = (wave >> 3) ? 1 : 2;
        f32x4 a4[2];
        #pragma unroll
        for (int i = 0; i < 2; i++) a4[i] = (f32x4){0.f, 0.f, 0.f, 0.f};
        #pragma unroll
        for (int ks = 0; ks < 8; ks++) {
            const size_t wo = (size_t)(j0 * 16 + l15) * 256 + ks * 32 + lq * 8;
            short8 bh = *(const short8*)&owh[wo];
            short8 bl = *(const short8*)&owl[wo];
            #pragma unroll
            for (int i = 0; i < 2; i++) {
                if (i < ni) {
                    short8 ah = *(const short8*)&sGh[(i0 + i) * 16 + l15][ks * 32 + lq * 8];
                    short8 al = *(const short8*)&sGl[(i0 + i) * 16 + l15][ks * 32 + lq * 8];
                    a4[i] = __builtin_amdgcn_mfma_f32_16x16x32_bf16(ah, bh, a4[i], 0, 0, 0);
                    a4[i] = __builtin_amdgcn_mfma_f32_16x16x32_bf16(ah, bl, a4[i], 0, 0, 0);
                    a4[i] = __builtin_amdgcn_mfma_f32_16x16x32_bf16(al, bh, a4[i], 0, 0, 0);
                }
            }
        }
        #pragma unroll
        for (int i = 0; i < 2; i++) {
            if (i < ni) {
                int row = (i0 + i) * 16 + lq * 4;
                int col = j0 * 16 + l15;
                float bb = outb[col];
                #pragma unroll
                for (int r = 0; r < 4; r++)
                    if (row + r < LL) {
                        float v = a4[i][r] + bb;
                        u16 hh, ll;
                        f2pair(v, &hh, &ll);
                        size_t fo = (size_t)b * 4352 + (row + r) * 128 + col;
                        Fh[fo] = hh;
                        Fl[fo] = ll;
                    }
            }
        }
    }
}

// ---------------------------------------------------------------------------
// Fallback sequential scan for general A (early-exits when A is uniform).
// ---------------------------------------------------------------------------
__global__ __launch_bounds__(256)
void scan_fb_k(const int* __restrict__ flag,
               const float* __restrict__ dBC,
               const u16*  __restrict__ Xh, const u16* __restrict__ Xl,
               const float* __restrict__ A,
               const float* __restrict__ DG,
               u16* __restrict__ Gh, u16* __restrict__ Gl)
{
    if (*flag != 0) return;
    const int b  = blockIdx.y;
    const int d0 = blockIdx.x * 64;
    const int tid = threadIdx.x;
    const int sub = tid & 15;
    const int pg  = tid >> 4;
    const int dbase = d0 + pg * 4;
    const int nA = sub * 4;

    float a[4][8], h[4][8];
    #pragma unroll
    for (int dd = 0; dd < 4; dd++) {
        const float* Ar = A + (size_t)(dbase + dd) * NN;
        float4 q0 = *(const float4*)(Ar + nA);
        float4 q1 = *(const float4*)(Ar + 64 + nA);
        a[dd][0]=q0.x; a[dd][1]=q0.y; a[dd][2]=q0.z; a[dd][3]=q0.w;
        a[dd][4]=q1.x; a[dd][5]=q1.y; a[dd][6]=q1.z; a[dd][7]=q1.w;
        #pragma unroll
        for (int j = 0; j < 8; j++) h[dd][j] = 0.f;
    }

    const float* pD  = dBC + (size_t)b * LL * 512 + dbase;
    const float* pBC = dBC + (size_t)b * LL * 512 + 256 + nA;
    const u16*  pXh = Xh  + (size_t)b * LL * 256 + dbase;
    const u16*  pXl = Xl  + (size_t)b * LL * 256 + dbase;
    const float* pG  = DG  + (size_t)b * LL * 512 + 256 + dbase;
    u16* pGh = Gh + (size_t)b * LL * 256 + dbase;
    u16* pGl = Gl + (size_t)b * LL * 256 + dbase;

    for (int l = 0; l < LL; l++) {
        float4  cD  = *(const float4*)(pD);
        ushort4 cXh = *(const ushort4*)(pXh);
        ushort4 cXl = *(const ushort4*)(pXl);
        float4 cB0 = *(const float4*)(pBC);
        float4 cB1 = *(const float4*)(pBC + 64);
        float4 cC0 = *(const float4*)(pBC + 128);
        float4 cC1 = *(const float4*)(pBC + 192);
        pD += 512; pBC += 512; pXh += 256; pXl += 256;

        float xv[4] = { bf2f(cXh.x) + bf2f(cXl.x), bf2f(cXh.y) + bf2f(cXl.y),
                        bf2f(cXh.z) + bf2f(cXl.z), bf2f(cXh.w) + bf2f(cXl.w) };
        float dl[4] = {cD.x, cD.y, cD.z, cD.w};
        float dx[4] = {cD.x * xv[0], cD.y * xv[1], cD.z * xv[2], cD.w * xv[3]};
        float bv[8] = {cB0.x,cB0.y,cB0.z,cB0.w,cB1.x,cB1.y,cB1.z,cB1.w};
        float cv[8] = {cC0.x,cC0.y,cC0.z,cC0.w,cC1.x,cC1.y,cC1.z,cC1.w};

        float accd[4] = {0.f, 0.f, 0.f, 0.f};
        #pragma unroll
        for (int dd = 0; dd < 4; dd++)
            #pragma unroll
            for (int j = 0; j < 8; j++) {
                float dA = __expf(dl[dd] * a[dd][j]);
                h[dd][j] = fmaf(dA, h[dd][j], dx[dd] * bv[j]);
                accd[dd] = fmaf(cv[j], h[dd][j], accd[dd]);
            }
        #pragma unroll
        for (int dd = 0; dd < 4; dd++) {
            float v = accd[dd];
            v += __shfl_xor(v, 1);
            v += __shfl_xor(v, 2);
            v += __shfl_xor(v, 4);
            v += __shfl_xor(v, 8);
            accd[dd] = v;
        }
        if (sub == 0) {
            float4 dg = *(const float4*)(pG);
            ushort4 oh, ol;
            float g0 = silu_f(accd[0]) * silu_f(dg.x);
            float g1 = silu_f(accd[1]) * silu_f(dg.y);
            float g2 = silu_f(accd[2]) * silu_f(dg.z);
            float g3 = silu_f(accd[3]) * silu_f(dg.w);
            f2pair(g0, &oh.x, &ol.x);
            f2pair(g1, &oh.y, &ol.y);
            f2pair(g2, &oh.z, &ol.z);
            f2pair(g3, &oh.w, &ol.w);
            *(ushort4*)pGh = oh;
            *(ushort4*)pGl = ol;
        }
        pG += 512; pGh += 256; pGl += 256;
    }
}

// ---------------------------------------------------------------------------
// Cold tail: gate (from scan_fb) @ out_w.T + out_b -> F bf16 pairs.
// Early-exits when A is uniform (hot path handled inside mega2_k).
// ---------------------------------------------------------------------------
__global__ __launch_bounds__(512)
void tail_cold_k(const int* __restrict__ flag,
                 const u16* __restrict__ gFh, const u16* __restrict__ gFl,
                 const u16* __restrict__ owh, const u16* __restrict__ owl,
                 const float* __restrict__ outb,
                 u16* __restrict__ Fh, u16* __restrict__ Fl)
{
    if (*flag != 0) return;
    const int b    = blockIdx.x;
    const int tid  = threadIdx.x;
    const int wave = tid >> 6;
    const int lane = tid & 63;
    const int l15  = lane & 15;
    const int lq   = lane >> 4;

    __shared__ u16 sGh[48][264];
    __shared__ u16 sGl[48][264];

    for (int idx = tid; idx < LL * 32; idx += 512) {
        int l = idx >> 5, c = (idx & 31) << 3;
        *(short8*)&sGh[l][c] = *(const short8*)&gFh[((size_t)b * LL + l) * 256 + c];
        *(short8*)&sGl[l][c] = *(const short8*)&gFl[((size_t)b * LL + l) * 256 + c];
    }
    {
        u16* zh = &sGh[34][0];
        u16* zl = &sGl[34][0];
        for (int idx = tid; idx < 14 * 264; idx += 512) {
            zh[idx] = 0;
            zl[idx] = 0;
        }
    }
    __syncthreads();

    const int j0 = wave;
    f32x4 a4[3];
    #pragma unroll
    for (int i = 0; i < 3; i++) a4[i] = (f32x4){0.f, 0.f, 0.f, 0.f};
    #pragma unroll
    for (int ks = 0; ks < 8; ks++) {
        const size_t wo = (size_t)(j0 * 16 + l15) * 256 + ks * 32 + lq * 8;
        short8 bh = *(const short8*)&owh[wo];
        short8 bl = *(const short8*)&owl[wo];
        #pragma unroll
        for (int i = 0; i < 3; i++) {
            short8 ah = *(const short8*)&sGh[i * 16 + l15][ks * 32 + lq * 8];
            short8 al = *(const short8*)&sGl[i * 16 + l15][ks * 32 + lq * 8];
            a4[i] = __builtin_amdgcn_mfma_f32_16x16x32_bf16(ah, bh, a4[i], 0, 0, 0);
            a4[i] = __builtin_amdgcn_mfma_f32_16x16x32_bf16(ah, bl, a4[i], 0, 0, 0);
            a4[i] = __builtin_amdgcn_mfma_f32_16x16x32_bf16(al, bh, a4[i], 0, 0, 0);
        }
    }
    #pragma unroll
    for (int i = 0; i < 3; i++) {
        int row = i * 16 + lq * 4;
        int col = j0 * 16 + l15;
        float bb = outb[col];
        #pragma unroll
        for (int r = 0; r < 4; r++)
            if (row + r < LL) {
                float v = a4[i][r] + bb;
                u16 hh, ll;
                f2pair(v, &hh, &ll);
                size_t fo = (size_t)b * 4352 + (row + r) * 128 + col;
                Fh[fo] = hh;
                Fl[fo] = ll;
            }
    }
}

// ---------------------------------------------------------------------------
// FNN stage 1 (MFMA split-bf16): partials[kc][b][o] = F[b] @ W1.T chunk.
// M=256, N=64, K=4352 in 17 chunks of 256.  Grid (4 Mtiles, 17 kc), 4 waves;
// wave w owns col-tile w (16 cols); fragments read direct from L2.
// ---------------------------------------------------------------------------
__global__ __launch_bounds__(256)
void fnn1_k(const u16* __restrict__ Fh, const u16* __restrict__ Fl,
            const u16* __restrict__ w1h, const u16* __restrict__ w1l,
            float* __restrict__ partials)
{
    const int mt   = blockIdx.x;        // rows mt*64 .. +63
    const int kc   = blockIdx.y;        // k chunk kc*256 .. +255
    const int wave = threadIdx.x >> 6;  // cols wave*16 .. +15
    const int lane = threadIdx.x & 63;
    const int l15  = lane & 15;
    const int lq   = lane >> 4;

    f32x4 acc[4];
    #pragma unroll
    for (int i = 0; i < 4; i++) acc[i] = (f32x4){0.f, 0.f, 0.f, 0.f};

    #pragma unroll
    for (int ks = 0; ks < 8; ks++) {
        const size_t wo = (size_t)(wave * 16 + l15) * 4352 + kc * 256 + ks * 32 + lq * 8;
        short8 bh = *(const short8*)&w1h[wo];
        short8 bl = *(const short8*)&w1l[wo];
        #pragma unroll
        for (int i = 0; i < 4; i++) {
            const size_t ao = (size_t)(mt * 64 + i * 16 + l15) * 4352 + kc * 256 + ks * 32 + lq * 8;
            short8 ah = *(const short8*)&Fh[ao];
            short8 al = *(const short8*)&Fl[ao];
            acc[i] = __builtin_amdgcn_mfma_f32_16x16x32_bf16(ah, bh, acc[i], 0, 0, 0);
            acc[i] = __builtin_amdgcn_mfma_f32_16x16x32_bf16(ah, bl, acc[i], 0, 0, 0);
            acc[i] = __builtin_amdgcn_mfma_f32_16x16x32_bf16(al, bh, acc[i], 0, 0, 0);
        }
    }
    #pragma unroll
    for (int i = 0; i < 4; i++) {
        int row = mt * 64 + i * 16 + lq * 4;
        int col = wave * 16 + l15;
        #pragma unroll
        for (int r = 0; r < 4; r++)
            partials[(size_t)kc * 16384 + (row + r) * 64 + col] = acc[i][r];
    }
}

// ---------------------------------------------------------------------------
// FNN stage 2: reduce partials, leaky, then @fnn2_w.T + b2 -> out[b][32].
// ---------------------------------------------------------------------------
__global__ __launch_bounds__(64)
void fnn2_k(const float* __restrict__ partials,
            const float* __restrict__ B1,
            const float* __restrict__ W2, const float* __restrict__ B2,
            float* __restrict__ out)
{
    int b = blockIdx.x;
    int t = threadIdx.x;
    __shared__ float s1[64];
    float acc = B1[t];
    #pragma unroll
    for (int kc = 0; kc < 17; kc++)
        acc += partials[(size_t)kc * 16384 + b * 64 + t];
    s1[t] = leaky_f(acc);
    __syncthreads();

    if (t < 32) {
        float acc2 = B2[t];
        const float* w2 = W2 + t * 64;
        #pragma unroll
        for (int j = 0; j < 64; j++) acc2 = fmaf(s1[j], w2[j], acc2);
        out[(size_t)b * 32 + t] = acc2;
    }
}

// ---------------------------------------------------------------------------
extern "C" void kernel_launch(void* const* d_in, const int* in_sizes, int n_in,
                              void* d_out, int out_size, void* d_ws, size_t ws_size,
                              hipStream_t stream)
{
    const float* x        = (const float*)d_in[0];
    const float* conv_w   = (const float*)d_in[1];
    const float* conv_b   = (const float*)d_in[2];
    const float* norm_w   = (const float*)d_in[3];
    const float* inp_w    = (const float*)d_in[4];
    const float* inp_b    = (const float*)d_in[5];
    const float* seqconv_w= (const float*)d_in[6];
    const float* seqconv_b= (const float*)d_in[7];
    const float* convlin_w= (const float*)d_in[8];
    const float* convlin_b= (const float*)d_in[9];
    const float* fc1_w    = (const float*)d_in[10];
    const float* fc1_b    = (const float*)d_in[11];
    const float* fc2_w    = (const float*)d_in[12];
    const float* fc2_b    = (const float*)d_in[13];
    const float* fc3_w    = (const float*)d_in[14];
    const float* fc3_b    = (const float*)d_in[15];
    const float* A        = (const float*)d_in[16];
    const float* D_w      = (const float*)d_in[17];
    const float* D_b      = (const float*)d_in[18];
    const float* out_w    = (const float*)d_in[19];
    const float* out_b    = (const float*)d_in[20];
    const float* fnn1_w   = (const float*)d_in[21];
    const float* fnn1_b   = (const float*)d_in[22];
    const float* fnn2_w   = (const float*)d_in[23];
    const float* fnn2_b   = (const float*)d_in[24];

    // ---- workspace layout (bytes) ----
    char* W = (char*)d_ws;
    float* buf1  = (float*)(W + 0);           // [8704,512] cold only: dgate at
                                              // cols 256+, bcpair in cols 0-255
    float* buf3  = (float*)(W + 17825792);    // [8704,512] delta (always);
                                              // B|C cold; partials later
    u16*   Fh    = (u16*)  (W + 35651584);    // [256,4352] F bf16 hi
    u16*   Fl    = (u16*)  (W + 37879808);    // [256,4352] F bf16 lo
    u16*   xc2h  = (u16*)  (W + 40108032);    // [8704,256] cold only
    u16*   xc2l  = (u16*)  (W + 44564480);    // [8704,256] cold only
    u16*   gateh = (u16*)  (W + 49020928);    // [8704,256] cold only
    u16*   gatel = (u16*)  (W + 53477376);    // [8704,256] cold only
    u16*   w1h   = (u16*)  (W + 57933824);    // [64,4352]
    u16*   w1l   = (u16*)  (W + 58490880);
    u16*   wc1h  = (u16*)  (W + 59047936);
    u16*   wc1l  = (u16*)  (W + 59179008);
    u16*   wc3h  = (u16*)  (W + 59310080);
    u16*   wc3l  = (u16*)  (W + 59572224);
    u16*   cvh   = (u16*)  (W + 59834368);
    u16*   cvl   = (u16*)  (W + 59965440);
    u16*   owh   = (u16*)  (W + 60096512);
    u16*   owl   = (u16*)  (W + 60162048);
    float* bias1 = (float*)(W + 60227584);
    float* bias3 = (float*)(W + 60229632);
    int*   uflag = (int*)  (W + 60231680);
    u16* bcpair = (u16*)buf1;                 // xp half of buf1 (cold only)
    float* partials = buf3;

    // weight prep (2240 blocks) + A-check (1)
    prep_k<<<2241, 256, 0, stream>>>(inp_w, D_w, fc1_w, fc2_w, fc3_w,
                                     convlin_w, out_w,
                                     inp_b, D_b, fc1_b, fc2_b, fc3_b,
                                     fnn1_w, A,
                                     wc1h, wc1l, wc3h, wc3l, cvh, cvl,
                                     owh, owl, w1h, w1l, bias1, bias3, uflag);

    // fused pipeline: conv+rmsnorm -> G1(inp|D) -> seqconv -> G2(convlin)
    // -> G3(fc) -> [M || scan-u] -> triangle+gate -> G4(out_w) -> F pairs
    mega2_k<<<NB, 1024, 0, stream>>>(uflag, x, conv_w, conv_b, norm_w,
                                     wc1h, wc1l, bias1,
                                     seqconv_w, seqconv_b,
                                     cvh, cvl, convlin_b, wc3h, wc3l, bias3,
                                     A, owh, owl, out_b,
                                     buf1, buf3, bcpair, xc2h, xc2l, Fh, Fl);

    // cold general-A path (early-exit when uniform)
    scan_fb_k<<<dim3(4, NB), 256, 0, stream>>>(uflag, buf3, xc2h, xc2l, A,
                                               buf1, gateh, gatel);
    tail_cold_k<<<NB, 512, 0, stream>>>(uflag, gateh, gatel, owh, owl, out_b,
                                        Fh, Fl);

    // FNN head: MFMA split-K fnn1 -> fp32 partials -> fnn2
    fnn1_k<<<dim3(4, 17), 256, 0, stream>>>(Fh, Fl, w1h, w1l, partials);
    fnn2_k<<<NB, 64, 0, stream>>>(partials, fnn1_b, fnn2_w, fnn2_b,
                                  (float*)d_out);
}

// Round 11
// 198.252 us; speedup vs baseline: 1.0205x; 1.0205x over previous
//
#include <hip/hip_runtime.h>
#include <math.h>

// ---------------------------------------------------------------------------
// SpectralGroupAttention: [prep: weight bf16-pairs + fnn1 transpose + A-check]
// -> [MEGA2 (1024 thr): conv1d+leaky+RMSNorm (wave-per-row, barrier-free) ->
//  GEMM(inp|D) -> seqconv -> GEMM(convlin) -> GEMM(fc1|2|3,softplus) ->
//  [M=C.B^T (waves 4-12)  ||  scan u/eS cumsum (threads 0-255)] ->
//  triangle+gate -> GEMM(out_w) -> fout; dgate fp32 LDS, delta via buf3] ->
// batch-grouped FNN head.
// Sequential fallback kept for general A (scan_fb + tail_cold, early-exit).
// GEMMs use split-bf16 (hi+lo, 3 MFMA products).
// B=256, L=34, d=128, di=256, N=128, M=8704.
// ---------------------------------------------------------------------------

#define NB    256
#define LL    34
#define DD    128
#define DI    256
#define NN    128
#define MM    (NB*LL)       // 8704

using u16 = unsigned short;
typedef __attribute__((ext_vector_type(8))) short short8;
typedef __attribute__((ext_vector_type(4))) float f32x4;

__device__ __forceinline__ float silu_f(float x)  { return x / (1.f + __expf(-x)); }
__device__ __forceinline__ float softplus_f(float x) {
    return fmaxf(x, 0.f) + __logf(1.f + __expf(-fabsf(x)));
}
__device__ __forceinline__ float leaky_f(float x) { return (x >= 0.f) ? x : 0.01f * x; }

__device__ __forceinline__ u16 f2bf(float x) {            // RNE fp32->bf16
    unsigned u = __float_as_uint(x);
    return (u16)((u + 0x7FFF + ((u >> 16) & 1)) >> 16);
}
__device__ __forceinline__ float bf2f(u16 h) {
    return __uint_as_float(((unsigned)h) << 16);
}
__device__ __forceinline__ void f2pair(float v, u16* h, u16* l) {
    u16 hh = f2bf(v);
    *h = hh;
    *l = f2bf(v - bf2f(hh));
}

// ---------------------------------------------------------------------------
// prep_k: weight bf16-pair conversion + bias concat (blocks [0,1152));
// fnn1_w transpose (blocks [1152,1220)); A-uniformity check (block 1220).
// ---------------------------------------------------------------------------
__global__ __launch_bounds__(256)
void prep_k(const float* __restrict__ inp_w, const float* __restrict__ D_w,
            const float* __restrict__ fc1_w, const float* __restrict__ fc2_w,
            const float* __restrict__ fc3_w, const float* __restrict__ convlin_w,
            const float* __restrict__ out_w,
            const float* __restrict__ inp_b, const float* __restrict__ D_b,
            const float* __restrict__ fc1_b, const float* __restrict__ fc2_b,
            const float* __restrict__ fc3_b,
            const float* __restrict__ W1, const float* __restrict__ A,
            u16* __restrict__ wc1h, u16* __restrict__ wc1l,
            u16* __restrict__ wc3h, u16* __restrict__ wc3l,
            u16* __restrict__ cvh,  u16* __restrict__ cvl,
            u16* __restrict__ owh,  u16* __restrict__ owl,
            float* __restrict__ bias1, float* __restrict__ bias3,
            float* __restrict__ W1T, int* __restrict__ flag)
{
    const int bx  = blockIdx.x;
    const int tid = threadIdx.x;
    __shared__ float tile[64][65];   // transpose branch only

    if (bx < 1152) {
        int i = bx * 256 + tid;
        if (i < 65536) {
            float v = (i < 32768) ? inp_w[i] : D_w[i - 32768];
            f2pair(v, &wc1h[i], &wc1l[i]);
        } else if (i < 196608) {
            int j = i - 65536;
            float v = (j < 65536) ? fc1_w[j] : (j < 98304 ? fc2_w[j - 65536] : fc3_w[j - 98304]);
            f2pair(v, &wc3h[j], &wc3l[j]);
        } else if (i < 262144) {
            int j = i - 196608;
            f2pair(convlin_w[j], &cvh[j], &cvl[j]);
        } else if (i < 294912) {
            int j = i - 262144;
            f2pair(out_w[j], &owh[j], &owl[j]);
        }
        if (i < 512)  bias1[i] = (i < 256) ? inp_b[i] : D_b[i - 256];
        else if (i < 1024) {
            int j = i - 512;
            bias3[j] = (j < 256) ? fc1_b[j] : (j < 384 ? fc2_b[j - 256] : fc3_b[j - 384]);
        }
    } else if (bx < 1220) {
        const int bt = bx - 1152;         // col tile: bt*64 .. +63
        for (int p = 0; p < 16; p++) {
            int idx = tid + p * 256;
            int r = idx >> 6, c = idx & 63;
            tile[r][c] = W1[(size_t)r * 4352 + bt * 64 + c];
        }
        __syncthreads();
        for (int p = 0; p < 16; p++) {
            int idx = tid + p * 256;
            int cc = idx >> 6, rr = idx & 63;
            W1T[(size_t)(bt * 64 + cc) * 64 + rr] = tile[rr][cc];
        }
    } else {
        __shared__ int s;
        if (tid == 0) s = 1;
        __syncthreads();
        bool ok = true;
        for (int k = 0; k < 128; k++) {
            int idx = tid + k * 256;
            ok &= (A[idx] == A[idx & ~127]);
        }
        if (!ok) s = 0;
        __syncthreads();
        if (tid == 0) *flag = s;
    }
}

// ---------------------------------------------------------------------------
// MEGA2: per-batch fused pipeline.  256 blocks x 1024 threads, ~142 KB LDS,
// 1 block/CU.
//   conv+leaky+rmsnorm (wave-per-row, 0 barriers) -> sXn pairs ->
//   G1 (inp|D; xp->sx, dgate->sDG fp32 LDS) -> seqconv -> xc pairs ->
//   G2 (convlin) -> xc2 pairs -> G3 (fc1|2|3; delta->buf3 global) ->
//   [cold: spill dgate/xc2/delta|B|C/BC to global, return] ->
//   [waves 4-12: M=C.B^T  ||  threads 0-255: u/eS cumsum (regs)] ->
//   triangle+gate (256 thr, static unroll) -> out-GEMM -> fout.
// ---------------------------------------------------------------------------
__global__ __launch_bounds__(1024, 1)
void mega2_k(const int* __restrict__ flag,
             const float* __restrict__ x,
             const float* __restrict__ cw, const float* __restrict__ cb,
             const float* __restrict__ nw,
             const u16* __restrict__ wc1h, const u16* __restrict__ wc1l,
             const float* __restrict__ bias1,
             const float* __restrict__ scw, const float* __restrict__ scb,
             const u16* __restrict__ cvh, const u16* __restrict__ cvl,
             const float* __restrict__ clb,
             const u16* __restrict__ wc3h, const u16* __restrict__ wc3l,
             const float* __restrict__ bias3,
             const float* __restrict__ A,
             const u16* __restrict__ owh, const u16* __restrict__ owl,
             const float* __restrict__ outb,
             float* __restrict__ buf1,           // cold: dgate spill cols 256+
             float* __restrict__ buf3,           // delta (always); B|C cold
             u16* __restrict__ bcpair,           // cold only
             u16* __restrict__ xc2h, u16* __restrict__ xc2l, // cold only
             float* __restrict__ fout)
{
    const int b    = blockIdx.x;
    const int tid  = threadIdx.x;
    const int wave = tid >> 6;
    const int lane = tid & 63;
    const int l15  = lane & 15;
    const int lq   = lane >> 4;

    // ---- LDS overlay plan (144944 B) ----
    // regionA [0,52224): {sx[34][264]f32 (35904) + sw[34][112]f32} ->
    //   {sXc pairs [48][264]} -> {sB/sBl/sC/sCl [48][136]} -> {gate pairs}
    // regionB [52224,102912): {sXn pairs [48][136] early} -> sX2 pairs [48][264]
    // regionC [102912,109576): sM [34][49] f32
    // regionD [109584,144944): sDG [34][260] f32   (dgate is 256 wide)
    __shared__ __align__(16) char smem[144944];
    float (*sx)[264] = (float (*)[264])(smem);
    float (*sw)[112] = (float (*)[112])(smem + 35904);
    u16 (*sXch)[264] = (u16 (*)[264])(smem);
    u16 (*sXcl)[264] = (u16 (*)[264])(smem + 25344);
    u16 (*sBh)[136]  = (u16 (*)[136])(smem);
    u16 (*sBl)[136]  = (u16 (*)[136])(smem + 13056);
    u16 (*sCh)[136]  = (u16 (*)[136])(smem + 26112);
    u16 (*sCl)[136]  = (u16 (*)[136])(smem + 39168);
    u16 (*sGh)[264]  = (u16 (*)[264])(smem);
    u16 (*sGl)[264]  = (u16 (*)[264])(smem + 25344);
    u16 (*sXnh)[136] = (u16 (*)[136])(smem + 52224);   // dead before sX2 writes
    u16 (*sXnl)[136] = (u16 (*)[136])(smem + 65280);
    u16 (*sX2h)[264] = (u16 (*)[264])(smem + 52224);
    u16 (*sX2l)[264] = (u16 (*)[264])(smem + 77568);
    float (*sM)[49]  = (float (*)[49])(smem + 102912);
    float (*sDG)[260]= (float (*)[260])(smem + 109584);

    const bool uni = (*flag != 0);

    // ---- stage seqconv weights + sx pad (independent of conv) ----
    for (int idx = tid; idx < LL * LL * 3; idx += 1024) {
        int lo = idx / 102;
        int rem = idx - lo * 102;
        int li = rem / 3;
        int k  = rem - li * 3;
        sw[li][lo * 3 + k] = scw[idx];
    }
    if (tid < LL) { sx[tid][0] = 0.f; sx[tid][257] = 0.f; }

    // ---- phase 0: conv1d(1->128,k20,s5)+leaky+RMSNorm -> sXn pairs.
    //      One row per WAVE (2 channels/lane, 64-lane butterfly = full
    //      128-ch reduction) -> zero barriers. ----
    {
        const int t = lane;
        #pragma unroll
        for (int pass = 0; pass < 3; pass++) {
            const int rr = pass * 16 + wave;
            if (rr < LL) {
                const float* xr = x + (size_t)b * 189 + rr * 5;
                float xv[20];
                #pragma unroll
                for (int k = 0; k < 20; k++) xv[k] = xr[k];
                float g0 = cb[t];
                float g1 = cb[t + 64];
                #pragma unroll
                for (int k = 0; k < 20; k++) {
                    g0 = fmaf(xv[k], cw[t * 20 + k], g0);
                    g1 = fmaf(xv[k], cw[(t + 64) * 20 + k], g1);
                }
                g0 = leaky_f(g0);
                g1 = leaky_f(g1);
                float s = fmaf(g1, g1, g0 * g0);
                #pragma unroll
                for (int m = 32; m >= 1; m >>= 1) s += __shfl_xor(s, m);
                float inv = 1.f / sqrtf(s * (1.f / 128.f) + 1e-5f);
                float v0 = g0 * inv * nw[t];
                float v1 = g1 * inv * nw[t + 64];
                f2pair(v0, &sXnh[rr][t], &sXnl[rr][t]);
                f2pair(v1, &sXnh[rr][t + 64], &sXnl[rr][t + 64]);
            }
        }
    }
    __syncthreads();

    // ---- G1: xp|dgate = xn @ [inp_w;D_w].T + bias1 (K=128, barrier-free) ----
    {
        const int c0 = wave * 32;
        f32x4 a1[3][2];
        #pragma unroll
        for (int i = 0; i < 3; i++)
            #pragma unroll
            for (int j = 0; j < 2; j++) a1[i][j] = (f32x4){0.f, 0.f, 0.f, 0.f};

        #pragma unroll
        for (int ks = 0; ks < 4; ks++) {
            short8 fh[3], fl[3];
            #pragma unroll
            for (int i = 0; i < 3; i++) {
                fh[i] = *(const short8*)&sXnh[i * 16 + l15][ks * 32 + lq * 8];
                fl[i] = *(const short8*)&sXnl[i * 16 + l15][ks * 32 + lq * 8];
            }
            #pragma unroll
            for (int j = 0; j < 2; j++) {
                const size_t wo = (size_t)(c0 + j * 16 + l15) * 128 + ks * 32 + lq * 8;
                short8 bh = *(const short8*)&wc1h[wo];
                short8 bl = *(const short8*)&wc1l[wo];
                #pragma unroll
                for (int i = 0; i < 3; i++) {
                    a1[i][j] = __builtin_amdgcn_mfma_f32_16x16x32_bf16(fh[i], bh, a1[i][j], 0, 0, 0);
                    a1[i][j] = __builtin_amdgcn_mfma_f32_16x16x32_bf16(fh[i], bl, a1[i][j], 0, 0, 0);
                    a1[i][j] = __builtin_amdgcn_mfma_f32_16x16x32_bf16(fl[i], bh, a1[i][j], 0, 0, 0);
                }
            }
        }
        #pragma unroll
        for (int i = 0; i < 3; i++) {
            int row = i * 16 + lq * 4;
            #pragma unroll
            for (int j = 0; j < 2; j++) {
                int col = c0 + j * 16 + l15;
                float bb = bias1[col];
                #pragma unroll
                for (int r = 0; r < 4; r++) {
                    float v = a1[i][j][r] + bb;
                    int rr = row + r;
                    if (rr < LL) {
                        if (col < 256) {
                            sx[rr][col + 1] = v;          // xp -> seqconv input
                        } else {
                            sDG[rr][col - 256] = v;       // dgate fp32 (hot)
                            if (!uni)
                                buf1[((size_t)b * LL + rr) * 512 + col] = v;
                        }
                    }
                }
            }
        }
    }
    __syncthreads();

    // ---- seqconv compute (rows split over 16 groups: 0,1 -> 3 rows,
    //      2..15 -> 2 rows) ----
    {
        const int tx  = tid & 63;
        const int ty  = tid >> 6;            // 0..15
        const int j0c = tx * 4;
        const int cbase = (ty < 2) ? ty * 3 : 6 + (ty - 2) * 2;
        const int ccnt  = (ty < 2) ? 3 : 2;

        float cacc[3][4];
        #pragma unroll
        for (int i = 0; i < 3; i++)
            #pragma unroll
            for (int jj = 0; jj < 4; jj++) cacc[i][jj] = 0.f;

        for (int li = 0; li < LL; li++) {
            float4 xa = *(const float4*)&sx[li][j0c];
            float2 xb = *(const float2*)&sx[li][j0c + 4];
            float xv[6] = {xa.x, xa.y, xa.z, xa.w, xb.x, xb.y};
            const float* swr = &sw[li][0];
            #pragma unroll
            for (int i = 0; i < 3; i++) {
                if (i < ccnt) {
                    int lo3 = (cbase + i) * 3;
                    float w0 = swr[lo3 + 0];
                    float w1 = swr[lo3 + 1];
                    float w2 = swr[lo3 + 2];
                    #pragma unroll
                    for (int jj = 0; jj < 4; jj++) {
                        cacc[i][jj] = fmaf(w0, xv[jj],     cacc[i][jj]);
                        cacc[i][jj] = fmaf(w1, xv[jj + 1], cacc[i][jj]);
                        cacc[i][jj] = fmaf(w2, xv[jj + 2], cacc[i][jj]);
                    }
                }
            }
        }
        __syncthreads();          // sx/sw reads done; regionA reusable

        #pragma unroll
        for (int i = 0; i < 3; i++) {
            if (i < ccnt) {
                int lo = cbase + i;
                float bb = scb[lo];
                ushort4 oh, ol;
                float v0 = silu_f(cacc[i][0] + bb);
                float v1 = silu_f(cacc[i][1] + bb);
                float v2 = silu_f(cacc[i][2] + bb);
                float v3 = silu_f(cacc[i][3] + bb);
                f2pair(v0, &oh.x, &ol.x);
                f2pair(v1, &oh.y, &ol.y);
                f2pair(v2, &oh.z, &ol.z);
                f2pair(v3, &oh.w, &ol.w);
                *(ushort4*)&sXch[lo][j0c] = oh;
                *(ushort4*)&sXcl[lo][j0c] = ol;
            }
        }
    }
    __syncthreads();

    // ---- G2: xc2 = xc @ convlin.T + bias (barrier-free K-loop),
    //      16 waves x 16-col tiles ----
    {
        const int c0 = wave * 16;
        f32x4 a2[3];
        #pragma unroll
        for (int i = 0; i < 3; i++) a2[i] = (f32x4){0.f, 0.f, 0.f, 0.f};

        #pragma unroll
        for (int ks = 0; ks < 8; ks++) {
            short8 fh[3], fl[3];
            #pragma unroll
            for (int i = 0; i < 3; i++) {
                fh[i] = *(const short8*)&sXch[i * 16 + l15][ks * 32 + lq * 8];
                fl[i] = *(const short8*)&sXcl[i * 16 + l15][ks * 32 + lq * 8];
            }
            const size_t wo = (size_t)(c0 + l15) * 256 + ks * 32 + lq * 8;
            short8 bh = *(const short8*)&cvh[wo];
            short8 bl = *(const short8*)&cvl[wo];
            #pragma unroll
            for (int i = 0; i < 3; i++) {
                a2[i] = __builtin_amdgcn_mfma_f32_16x16x32_bf16(fh[i], bh, a2[i], 0, 0, 0);
                a2[i] = __builtin_amdgcn_mfma_f32_16x16x32_bf16(fh[i], bl, a2[i], 0, 0, 0);
                a2[i] = __builtin_amdgcn_mfma_f32_16x16x32_bf16(fl[i], bh, a2[i], 0, 0, 0);
            }
        }
        #pragma unroll
        for (int i = 0; i < 3; i++) {
            int row = i * 16 + lq * 4;
            int col = c0 + l15;
            float bb = clb[col];
            #pragma unroll
            for (int r = 0; r < 4; r++) {
                float v = a2[i][r] + bb;
                u16 hh, ll;
                f2pair(v, &hh, &ll);
                sX2h[row + r][col] = hh;
                sX2l[row + r][col] = ll;
                if (!uni && (row + r) < LL) {
                    xc2h[(size_t)(b * LL + row + r) * 256 + col] = hh;
                    xc2l[(size_t)(b * LL + row + r) * 256 + col] = ll;
                }
            }
        }
    }
    __syncthreads();

    // ---- G3: delta|B|C = xc2 @ [fc1;fc2;fc3].T + bias (barrier-free K),
    //      16 waves x 32-col tiles; delta -> buf3 (global, always) ----
    {
        const int c0 = wave * 32;
        f32x4 a3[3][2];
        #pragma unroll
        for (int i = 0; i < 3; i++)
            #pragma unroll
            for (int j = 0; j < 2; j++) a3[i][j] = (f32x4){0.f, 0.f, 0.f, 0.f};

        #pragma unroll
        for (int ks = 0; ks < 8; ks++) {
            short8 fh[3], fl[3];
            #pragma unroll
            for (int i = 0; i < 3; i++) {
                fh[i] = *(const short8*)&sX2h[i * 16 + l15][ks * 32 + lq * 8];
                fl[i] = *(const short8*)&sX2l[i * 16 + l15][ks * 32 + lq * 8];
            }
            #pragma unroll
            for (int j = 0; j < 2; j++) {
                const size_t wo = (size_t)(c0 + j * 16 + l15) * 256 + ks * 32 + lq * 8;
                short8 bh = *(const short8*)&wc3h[wo];
                short8 bl = *(const short8*)&wc3l[wo];
                #pragma unroll
                for (int i = 0; i < 3; i++) {
                    a3[i][j] = __builtin_amdgcn_mfma_f32_16x16x32_bf16(fh[i], bh, a3[i][j], 0, 0, 0);
                    a3[i][j] = __builtin_amdgcn_mfma_f32_16x16x32_bf16(fh[i], bl, a3[i][j], 0, 0, 0);
                    a3[i][j] = __builtin_amdgcn_mfma_f32_16x16x32_bf16(fl[i], bh, a3[i][j], 0, 0, 0);
                }
            }
        }
        #pragma unroll
        for (int i = 0; i < 3; i++) {
            int row = i * 16 + lq * 4;
            #pragma unroll
            for (int j = 0; j < 2; j++) {
                int col = c0 + j * 16 + l15;
                float bb = bias3[col];
                #pragma unroll
                for (int r = 0; r < 4; r++) {
                    float v = a3[i][j][r] + bb;
                    int rr = row + r;
                    if (col < 256) {
                        v = softplus_f(v);
                        if (rr < LL) buf3[((size_t)b * LL + rr) * 512 + col] = v;
                    } else {
                        u16 hh, ll;
                        f2pair(v, &hh, &ll);
                        int cc = col & 127;
                        if (col < 384) { sBh[rr][cc] = hh; sBl[rr][cc] = ll; }
                        else           { sCh[rr][cc] = hh; sCl[rr][cc] = ll; }
                        if (!uni && rr < LL) {
                            buf3[((size_t)b * LL + rr) * 512 + col] = v;
                            u16* rb = bcpair + ((size_t)b * LL + rr) * 1024
                                      + ((col < 384) ? 0 : 256) + cc;
                            rb[0]   = hh;
                            rb[128] = ll;
                        }
                    }
                }
            }
        }
    }
    __syncthreads();
    if (!uni) return;             // cold path -> scan_fb + tail_cold

    // ---- OVERLAPPED PHASE:
    //      threads 0-255 (waves 0-3): scan u/eS cumsum into registers
    //        (reads buf3 delta + sX2 + A -- no dependence on sM);
    //      waves 4-12: M = C.B^T (9 tiles, one per wave).
    //      Disjoint thread sets; u/eS stay live across the barrier
    //      (~68 extra VGPRs, under the 128 cap at 1024 thr). ----
    float u[LL], eS[LL];
    if (tid < 256) {
        const int d = tid;
        const float a_d = A[(size_t)d * NN];
        const float* pDel = buf3 + (size_t)b * LL * 512 + d;    // stride 512
        float S = 0.f;
        #pragma unroll
        for (int l = 0; l < LL; l++) {
            float dl = pDel[l * 512];
            S = fmaf(dl, a_d, S);
            eS[l] = __expf(S);
            float xv = bf2f(sX2h[l][d]) + bf2f(sX2l[l][d]);
            u[l] = __expf(-S) * dl * xv;
        }
    } else if (wave >= 4 && wave < 13) {
        int tt = wave - 4;
        int ti = tt / 3, tj = tt - ti * 3;
        f32x4 acc = (f32x4){0.f, 0.f, 0.f, 0.f};
        #pragma unroll
        for (int ks = 0; ks < 4; ks++) {
            short8 ch = *(const short8*)&sCh[ti * 16 + l15][ks * 32 + lq * 8];
            short8 cl = *(const short8*)&sCl[ti * 16 + l15][ks * 32 + lq * 8];
            short8 bh = *(const short8*)&sBh[tj * 16 + l15][ks * 32 + lq * 8];
            short8 bl = *(const short8*)&sBl[tj * 16 + l15][ks * 32 + lq * 8];
            acc = __builtin_amdgcn_mfma_f32_16x16x32_bf16(ch, bh, acc, 0, 0, 0);
            acc = __builtin_amdgcn_mfma_f32_16x16x32_bf16(ch, bl, acc, 0, 0, 0);
            acc = __builtin_amdgcn_mfma_f32_16x16x32_bf16(cl, bh, acc, 0, 0, 0);
        }
        #pragma unroll
        for (int r = 0; r < 4; r++) {
            int row = ti * 16 + lq * 4 + r;
            if (row < LL) sM[row][tj * 16 + l15] = acc[r];
        }
    }
    __syncthreads();

    // ---- triangle + gate (threads 0-255); waves 4-15 zero gate pad rows ----
    if (tid < 256) {
        const int d = tid;
        #pragma unroll
        for (int l = 0; l < LL; l++) {
            float acc = 0.f;
            for (int t = 0; t <= l; t++) acc = fmaf(sM[l][t], u[t], acc);
            float xs = eS[l] * acc;
            float g = silu_f(xs) * silu_f(sDG[l][d]);
            u16 hh, ll2;
            f2pair(g, &hh, &ll2);
            sGh[l][d] = hh;
            sGl[l][d] = ll2;
        }
    } else {
        // zero gate rows 34..47 (contiguous 14*264 u16 per array)
        u16* zh = &sGh[34][0];
        u16* zl = &sGl[34][0];
        for (int idx = tid - 256; idx < 14 * 264; idx += 768) {
            zh[idx] = 0;
            zl[idx] = 0;
        }
    }
    __syncthreads();

    // ---- fout = gate @ out_w.T + out_b -> global.  16 waves:
    //      waves 0-7 -> i in {0,1}; waves 8-15 -> i = 2 (same col tile). ----
    {
        const int j0 = wave & 7;
        const int i0 = (wave >> 3) ? 2 : 0;
        const int ni = (wave >> 3) ? 1 : 2;
        f32x4 a4[2];
        #pragma unroll
        for (int i = 0; i < 2; i++) a4[i] = (f32x4){0.f, 0.f, 0.f, 0.f};
        #pragma unroll
        for (int ks = 0; ks < 8; ks++) {
            const size_t wo = (size_t)(j0 * 16 + l15) * 256 + ks * 32 + lq * 8;
            short8 bh = *(const short8*)&owh[wo];
            short8 bl = *(const short8*)&owl[wo];
            #pragma unroll
            for (int i = 0; i < 2; i++) {
                if (i < ni) {
                    short8 ah = *(const short8*)&sGh[(i0 + i) * 16 + l15][ks * 32 + lq * 8];
                    short8 al = *(const short8*)&sGl[(i0 + i) * 16 + l15][ks * 32 + lq * 8];
                    a4[i] = __builtin_amdgcn_mfma_f32_16x16x32_bf16(ah, bh, a4[i], 0, 0, 0);
                    a4[i] = __builtin_amdgcn_mfma_f32_16x16x32_bf16(ah, bl, a4[i], 0, 0, 0);
                    a4[i] = __builtin_amdgcn_mfma_f32_16x16x32_bf16(al, bh, a4[i], 0, 0, 0);
                }
            }
        }
        #pragma unroll
        for (int i = 0; i < 2; i++) {
            if (i < ni) {
                int row = (i0 + i) * 16 + lq * 4;
                int col = j0 * 16 + l15;
                float bb = outb[col];
                #pragma unroll
                for (int r = 0; r < 4; r++)
                    if (row + r < LL)
                        fout[(size_t)(b * LL + row + r) * 128 + col] = a4[i][r] + bb;
            }
        }
    }
}

// ---------------------------------------------------------------------------
// Fallback sequential scan for general A (early-exits when A is uniform).
// ---------------------------------------------------------------------------
__global__ __launch_bounds__(256)
void scan_fb_k(const int* __restrict__ flag,
               const float* __restrict__ dBC,
               const u16*  __restrict__ Xh, const u16* __restrict__ Xl,
               const float* __restrict__ A,
               const float* __restrict__ DG,
               u16* __restrict__ Gh, u16* __restrict__ Gl)
{
    if (*flag != 0) return;
    const int b  = blockIdx.y;
    const int d0 = blockIdx.x * 64;
    const int tid = threadIdx.x;
    const int sub = tid & 15;
    const int pg  = tid >> 4;
    const int dbase = d0 + pg * 4;
    const int nA = sub * 4;

    float a[4][8], h[4][8];
    #pragma unroll
    for (int dd = 0; dd < 4; dd++) {
        const float* Ar = A + (size_t)(dbase + dd) * NN;
        float4 q0 = *(const float4*)(Ar + nA);
        float4 q1 = *(const float4*)(Ar + 64 + nA);
        a[dd][0]=q0.x; a[dd][1]=q0.y; a[dd][2]=q0.z; a[dd][3]=q0.w;
        a[dd][4]=q1.x; a[dd][5]=q1.y; a[dd][6]=q1.z; a[dd][7]=q1.w;
        #pragma unroll
        for (int j = 0; j < 8; j++) h[dd][j] = 0.f;
    }

    const float* pD  = dBC + (size_t)b * LL * 512 + dbase;
    const float* pBC = dBC + (size_t)b * LL * 512 + 256 + nA;
    const u16*  pXh = Xh  + (size_t)b * LL * 256 + dbase;
    const u16*  pXl = Xl  + (size_t)b * LL * 256 + dbase;
    const float* pG  = DG  + (size_t)b * LL * 512 + 256 + dbase;
    u16* pGh = Gh + (size_t)b * LL * 256 + dbase;
    u16* pGl = Gl + (size_t)b * LL * 256 + dbase;

    for (int l = 0; l < LL; l++) {
        float4  cD  = *(const float4*)(pD);
        ushort4 cXh = *(const ushort4*)(pXh);
        ushort4 cXl = *(const ushort4*)(pXl);
        float4 cB0 = *(const float4*)(pBC);
        float4 cB1 = *(const float4*)(pBC + 64);
        float4 cC0 = *(const float4*)(pBC + 128);
        float4 cC1 = *(const float4*)(pBC + 192);
        pD += 512; pBC += 512; pXh += 256; pXl += 256;

        float xv[4] = { bf2f(cXh.x) + bf2f(cXl.x), bf2f(cXh.y) + bf2f(cXl.y),
                        bf2f(cXh.z) + bf2f(cXl.z), bf2f(cXh.w) + bf2f(cXl.w) };
        float dl[4] = {cD.x, cD.y, cD.z, cD.w};
        float dx[4] = {cD.x * xv[0], cD.y * xv[1], cD.z * xv[2], cD.w * xv[3]};
        float bv[8] = {cB0.x,cB0.y,cB0.z,cB0.w,cB1.x,cB1.y,cB1.z,cB1.w};
        float cv[8] = {cC0.x,cC0.y,cC0.z,cC0.w,cC1.x,cC1.y,cC1.z,cC1.w};

        float accd[4] = {0.f, 0.f, 0.f, 0.f};
        #pragma unroll
        for (int dd = 0; dd < 4; dd++)
            #pragma unroll
            for (int j = 0; j < 8; j++) {
                float dA = __expf(dl[dd] * a[dd][j]);
                h[dd][j] = fmaf(dA, h[dd][j], dx[dd] * bv[j]);
                accd[dd] = fmaf(cv[j], h[dd][j], accd[dd]);
            }
        #pragma unroll
        for (int dd = 0; dd < 4; dd++) {
            float v = accd[dd];
            v += __shfl_xor(v, 1);
            v += __shfl_xor(v, 2);
            v += __shfl_xor(v, 4);
            v += __shfl_xor(v, 8);
            accd[dd] = v;
        }
        if (sub == 0) {
            float4 dg = *(const float4*)(pG);
            ushort4 oh, ol;
            float g0 = silu_f(accd[0]) * silu_f(dg.x);
            float g1 = silu_f(accd[1]) * silu_f(dg.y);
            float g2 = silu_f(accd[2]) * silu_f(dg.z);
            float g3 = silu_f(accd[3]) * silu_f(dg.w);
            f2pair(g0, &oh.x, &ol.x);
            f2pair(g1, &oh.y, &ol.y);
            f2pair(g2, &oh.z, &ol.z);
            f2pair(g3, &oh.w, &ol.w);
            *(ushort4*)pGh = oh;
            *(ushort4*)pGl = ol;
        }
        pG += 512; pGh += 256; pGl += 256;
    }
}

// ---------------------------------------------------------------------------
// Cold tail: gate (from scan_fb) @ out_w.T + out_b -> fout.  Early-exits
// when A is uniform (hot path handled inside mega2_k).
// ---------------------------------------------------------------------------
__global__ __launch_bounds__(512)
void tail_cold_k(const int* __restrict__ flag,
                 const u16* __restrict__ gFh, const u16* __restrict__ gFl,
                 const u16* __restrict__ owh, const u16* __restrict__ owl,
                 const float* __restrict__ outb,
                 float* __restrict__ fout)
{
    if (*flag != 0) return;
    const int b    = blockIdx.x;
    const int tid  = threadIdx.x;
    const int wave = tid >> 6;
    const int lane = tid & 63;
    const int l15  = lane & 15;
    const int lq   = lane >> 4;

    __shared__ u16 sGh[48][264];
    __shared__ u16 sGl[48][264];

    for (int idx = tid; idx < LL * 32; idx += 512) {
        int l = idx >> 5, c = (idx & 31) << 3;
        *(short8*)&sGh[l][c] = *(const short8*)&gFh[((size_t)b * LL + l) * 256 + c];
        *(short8*)&sGl[l][c] = *(const short8*)&gFl[((size_t)b * LL + l) * 256 + c];
    }
    {
        u16* zh = &sGh[34][0];
        u16* zl = &sGl[34][0];
        for (int idx = tid; idx < 14 * 264; idx += 512) {
            zh[idx] = 0;
            zl[idx] = 0;
        }
    }
    __syncthreads();

    const int j0 = wave;
    f32x4 a4[3];
    #pragma unroll
    for (int i = 0; i < 3; i++) a4[i] = (f32x4){0.f, 0.f, 0.f, 0.f};
    #pragma unroll
    for (int ks = 0; ks < 8; ks++) {
        const size_t wo = (size_t)(j0 * 16 + l15) * 256 + ks * 32 + lq * 8;
        short8 bh = *(const short8*)&owh[wo];
        short8 bl = *(const short8*)&owl[wo];
        #pragma unroll
        for (int i = 0; i < 3; i++) {
            short8 ah = *(const short8*)&sGh[i * 16 + l15][ks * 32 + lq * 8];
            short8 al = *(const short8*)&sGl[i * 16 + l15][ks * 32 + lq * 8];
            a4[i] = __builtin_amdgcn_mfma_f32_16x16x32_bf16(ah, bh, a4[i], 0, 0, 0);
            a4[i] = __builtin_amdgcn_mfma_f32_16x16x32_bf16(ah, bl, a4[i], 0, 0, 0);
            a4[i] = __builtin_amdgcn_mfma_f32_16x16x32_bf16(al, bh, a4[i], 0, 0, 0);
        }
    }
    #pragma unroll
    for (int i = 0; i < 3; i++) {
        int row = i * 16 + lq * 4;
        int col = j0 * 16 + l15;
        float bb = outb[col];
        #pragma unroll
        for (int r = 0; r < 4; r++)
            if (row + r < LL)
                fout[(size_t)(b * LL + row + r) * 128 + col] = a4[i][r] + bb;
    }
}

// ---------------------------------------------------------------------------
// FNN stage 1: split-K partials (deterministic), batch-grouped so W1T is
// streamed 17 MB total (vs 285 MB for per-batch fusion).
// ---------------------------------------------------------------------------
__global__ __launch_bounds__(256)
void fnn1_k(const float* __restrict__ F, const float* __restrict__ W1T,
            float* __restrict__ partials)
{
    const int btile = blockIdx.x;
    const int kc    = blockIdx.y;
    const int tid   = threadIdx.x;
    __shared__ float sf[16][260];
    for (int i = tid; i < 16 * 256; i += 256) {
        int r = i >> 8, c = i & 255;
        sf[r][c] = F[(size_t)(btile * 16 + r) * 4352 + kc * 256 + c];
    }
    __syncthreads();

    const int o  = tid & 63;
    const int bq = tid >> 6;
    const float* w = W1T + (size_t)(kc * 256) * 64 + o;
    float acc[4] = {0.f, 0.f, 0.f, 0.f};
    for (int k = 0; k < 256; k += 4) {
        float w0 = w[(size_t)(k + 0) * 64];
        float w1 = w[(size_t)(k + 1) * 64];
        float w2 = w[(size_t)(k + 2) * 64];
        float w3 = w[(size_t)(k + 3) * 64];
        #pragma unroll
        for (int bj = 0; bj < 4; bj++) {
            float4 f4 = *(const float4*)&sf[bq * 4 + bj][k];
            acc[bj] = fmaf(w0, f4.x, acc[bj]);
            acc[bj] = fmaf(w1, f4.y, acc[bj]);
            acc[bj] = fmaf(w2, f4.z, acc[bj]);
            acc[bj] = fmaf(w3, f4.w, acc[bj]);
        }
    }
    #pragma unroll
    for (int bj = 0; bj < 4; bj++)
        partials[(size_t)kc * 16384 + (btile * 16 + bq * 4 + bj) * 64 + o] = acc[bj];
}

// ---------------------------------------------------------------------------
// FNN stage 2: reduce partials, leaky, then @fnn2_w.T + b2 -> out[b][32].
// ---------------------------------------------------------------------------
__global__ __launch_bounds__(64)
void fnn2_k(const float* __restrict__ partials,
            const float* __restrict__ B1,
            const float* __restrict__ W2, const float* __restrict__ B2,
            float* __restrict__ out)
{
    int b = blockIdx.x;
    int t = threadIdx.x;
    __shared__ float s1[64];
    float acc = B1[t];
    #pragma unroll
    for (int kc = 0; kc < 17; kc++)
        acc += partials[(size_t)kc * 16384 + b * 64 + t];
    s1[t] = leaky_f(acc);
    __syncthreads();

    if (t < 32) {
        float acc2 = B2[t];
        const float* w2 = W2 + t * 64;
        #pragma unroll
        for (int j = 0; j < 64; j++) acc2 = fmaf(s1[j], w2[j], acc2);
        out[(size_t)b * 32 + t] = acc2;
    }
}

// ---------------------------------------------------------------------------
extern "C" void kernel_launch(void* const* d_in, const int* in_sizes, int n_in,
                              void* d_out, int out_size, void* d_ws, size_t ws_size,
                              hipStream_t stream)
{
    const float* x        = (const float*)d_in[0];
    const float* conv_w   = (const float*)d_in[1];
    const float* conv_b   = (const float*)d_in[2];
    const float* norm_w   = (const float*)d_in[3];
    const float* inp_w    = (const float*)d_in[4];
    const float* inp_b    = (const float*)d_in[5];
    const float* seqconv_w= (const float*)d_in[6];
    const float* seqconv_b= (const float*)d_in[7];
    const float* convlin_w= (const float*)d_in[8];
    const float* convlin_b= (const float*)d_in[9];
    const float* fc1_w    = (const float*)d_in[10];
    const float* fc1_b    = (const float*)d_in[11];
    const float* fc2_w    = (const float*)d_in[12];
    const float* fc2_b    = (const float*)d_in[13];
    const float* fc3_w    = (const float*)d_in[14];
    const float* fc3_b    = (const float*)d_in[15];
    const float* A        = (const float*)d_in[16];
    const float* D_w      = (const float*)d_in[17];
    const float* D_b      = (const float*)d_in[18];
    const float* out_w    = (const float*)d_in[19];
    const float* out_b    = (const float*)d_in[20];
    const float* fnn1_w   = (const float*)d_in[21];
    const float* fnn1_b   = (const float*)d_in[22];
    const float* fnn2_w   = (const float*)d_in[23];
    const float* fnn2_b   = (const float*)d_in[24];

    // ---- workspace layout (bytes) ----
    char* W = (char*)d_ws;
    float* buf1  = (float*)(W + 0);           // [8704,512] cold only: dgate at
                                              // cols 256+, bcpair in cols 0-255
    float* buf3  = (float*)(W + 17825792);    // [8704,512] delta (always);
                                              // B|C cold; partials later
    float* fout  = (float*)(W + 35651584);    // [8704,128] fp32
    u16*   xc2h  = (u16*)  (W + 37879808);    // [8704,256] cold only
    u16*   xc2l  = (u16*)  (W + 42336256);    // [8704,256] cold only
    u16*   gateh = (u16*)  (W + 44564480);    // [8704,256] cold only
    u16*   gatel = (u16*)  (W + 49020928);    // [8704,256] cold only
    float* w1t   = (float*)(W + 53477376);    // [4352,64]
    u16*   wc1h  = (u16*)  (W + 54591488);
    u16*   wc1l  = (u16*)  (W + 54722560);
    u16*   wc3h  = (u16*)  (W + 54853632);
    u16*   wc3l  = (u16*)  (W + 55115776);
    u16*   cvh   = (u16*)  (W + 55377920);
    u16*   cvl   = (u16*)  (W + 55508992);
    u16*   owh   = (u16*)  (W + 55640064);
    u16*   owl   = (u16*)  (W + 55705600);
    float* bias1 = (float*)(W + 55771136);
    float* bias3 = (float*)(W + 55773184);
    int*   uflag = (int*)  (W + 55775232);
    u16* bcpair = (u16*)buf1;                 // xp half of buf1 (cold only)
    float* partials = buf3;

    // weight prep (1152 blocks) + fnn1_w transpose (68) + A-check (1)
    prep_k<<<1221, 256, 0, stream>>>(inp_w, D_w, fc1_w, fc2_w, fc3_w,
                                     convlin_w, out_w,
                                     inp_b, D_b, fc1_b, fc2_b, fc3_b,
                                     fnn1_w, A,
                                     wc1h, wc1l, wc3h, wc3l, cvh, cvl,
                                     owh, owl, bias1, bias3, w1t, uflag);

    // fused pipeline: conv+rmsnorm -> G1(inp|D) -> seqconv -> G2(convlin)
    // -> G3(fc) -> [M || scan-u] -> triangle+gate -> G4(out_w) -> fout
    mega2_k<<<NB, 1024, 0, stream>>>(uflag, x, conv_w, conv_b, norm_w,
                                     wc1h, wc1l, bias1,
                                     seqconv_w, seqconv_b,
                                     cvh, cvl, convlin_b, wc3h, wc3l, bias3,
                                     A, owh, owl, out_b,
                                     buf1, buf3, bcpair, xc2h, xc2l, fout);

    // cold general-A path (early-exit when uniform)
    scan_fb_k<<<dim3(4, NB), 256, 0, stream>>>(uflag, buf3, xc2h, xc2l, A,
                                               buf1, gateh, gatel);
    tail_cold_k<<<NB, 512, 0, stream>>>(uflag, gateh, gatel, owh, owl, out_b,
                                        fout);

    // FNN head (batch-grouped)
    fnn1_k<<<dim3(16, 17), 256, 0, stream>>>(fout, w1t, partials);
    fnn2_k<<<NB, 64, 0, stream>>>(partials, fnn1_b, fnn2_w, fnn2_b,
                                  (float*)d_out);
}